// Round 3
// baseline (481.938 us; speedup 1.0000x reference)
//
#include <hip/hip_runtime.h>

#define EPS 1e-5f
#define NDOM 8
#define NB 64
#define NC 256
#define NH 32
#define NW 128
#define HW (NH * NW)
#define NROW (NB * NC)          // 16384 (b,c) rows
#define ROWS_PER_BLK 8

// Native 4-float vector type usable with __builtin_nontemporal_store.
typedef float vfloat4 __attribute__((ext_vector_type(4)));

// Workspace layout (all regions fully overwritten each launch -> poison-safe):
//   partial      : float2[NB*NC]    per-(b,c) row (sum, sumsq)
//   scale_shift  : float2[NDOM*NC]  per-(domain,c) (scale, shift)

// Kernel 1: one WAVE per (b,c) row. 2048 blocks x 512 threads (8 waves).
// Pure in-wave shuffle reduction: no LDS, no __syncthreads.
__global__ __launch_bounds__(512) void row_stats(
    const float* __restrict__ x, float2* __restrict__ partial) {
    const int wave = threadIdx.x >> 6;               // 0..7
    const int lane = threadIdx.x & 63;
    const int bc   = blockIdx.x * ROWS_PER_BLK + wave;

    const vfloat4* xp = (const vfloat4*)(x + (size_t)bc * HW);
    float s = 0.f, sq = 0.f;
    // 4096 floats/row = 1024 float4 / 64 lanes = 16 float4 per lane.
#pragma unroll
    for (int k = 0; k < 16; ++k) {
        vfloat4 v = xp[lane + k * 64];
        s  += v.x + v.y + v.z + v.w;
        sq += v.x * v.x + v.y * v.y + v.z * v.z + v.w * v.w;
    }
    for (int off = 32; off > 0; off >>= 1) {
        s  += __shfl_down(s, off, 64);
        sq += __shfl_down(sq, off, 64);
    }
    if (lane == 0) partial[bc] = make_float2(s, sq);
}

// Kernel 2 (tiny): reduce partials over samples of each domain, emit
// per-(domain, channel) scale/shift. Grid: NDOM blocks x NC threads.
__global__ __launch_bounds__(NC) void finalize_stats(
    const float2* __restrict__ partial, const int* __restrict__ dom,
    const float* __restrict__ wgt, const float* __restrict__ bia,
    float2* __restrict__ scale_shift) {
    const int d = blockIdx.x;      // 0..NDOM-1
    const int c = threadIdx.x;     // 0..NC-1

    float S = 0.f, SQ = 0.f;
    int n = 0;
    for (int b = 0; b < NB; ++b) {
        if (dom[b] - 1 == d) {                 // dom[] is uniform -> scalar load
            float2 p = partial[b * NC + c];    // coalesced across threads
            S += p.x;
            SQ += p.y;
            ++n;
        }
    }
    const float cnt   = fmaxf((float)n * (float)HW, 1.0f);
    const float mean  = S / cnt;
    const float var   = SQ / cnt - mean * mean;
    const float inv   = rsqrtf(var + EPS);
    const float scale = wgt[c] * inv;
    scale_shift[d * NC + c] = make_float2(scale, bia[c] - mean * scale);
}

// Kernel 3: normalize 8 contiguous rows (same b, channels c0..c0+7 -> one
// contiguous 128 KiB stream) per 512-thread block. Reverse block order
// (hottest x rows re-read first while still L3-resident); non-temporal
// stores so out pollutes the Infinity Cache as little as possible.
__global__ __launch_bounds__(512) void norm_kernel(
    const float* __restrict__ x, const int* __restrict__ dom,
    const float2* __restrict__ scale_shift, float* __restrict__ out) {
    const int blk = (NROW / ROWS_PER_BLK) - 1 - blockIdx.x;   // reverse
    const int bc0 = blk * ROWS_PER_BLK;
    const int b   = bc0 / NC;
    const int c0  = bc0 % NC;

    const int d = dom[b] - 1;                  // uniform -> scalar load
    float sc[ROWS_PER_BLK], sh[ROWS_PER_BLK];
#pragma unroll
    for (int r = 0; r < ROWS_PER_BLK; ++r) {   // uniform -> scalar loads
        float2 t = scale_shift[d * NC + c0 + r];
        sc[r] = t.x;
        sh[r] = t.y;
    }

    const vfloat4* xp = (const vfloat4*)(x + (size_t)bc0 * HW);
    vfloat4*       op = (vfloat4*)(out + (size_t)bc0 * HW);
    // 8 rows x 1024 float4 = 8192 float4 / 512 threads = 16 per thread.
#pragma unroll
    for (int r = 0; r < ROWS_PER_BLK; ++r) {
#pragma unroll
        for (int k = 0; k < 2; ++k) {
            const int i = r * (HW / 4) + threadIdx.x + k * 512;
            vfloat4 v = xp[i];
            v.x = v.x * sc[r] + sh[r];
            v.y = v.y * sc[r] + sh[r];
            v.z = v.z * sc[r] + sh[r];
            v.w = v.w * sc[r] + sh[r];
            __builtin_nontemporal_store(v, &op[i]);
        }
    }
}

extern "C" void kernel_launch(void* const* d_in, const int* in_sizes, int n_in,
                              void* d_out, int out_size, void* d_ws, size_t ws_size,
                              hipStream_t stream) {
    const float* x   = (const float*)d_in[0];
    const float* wgt = (const float*)d_in[1];
    const float* bia = (const float*)d_in[2];
    const int*   dom = (const int*)d_in[3];
    float* out = (float*)d_out;

    float2* partial     = (float2*)d_ws;             // [NB*NC]
    float2* scale_shift = partial + NB * NC;         // [NDOM*NC]

    row_stats<<<NROW / ROWS_PER_BLK, 512, 0, stream>>>(x, partial);
    finalize_stats<<<NDOM, NC, 0, stream>>>(partial, dom, wgt, bia, scale_shift);
    norm_kernel<<<NROW / ROWS_PER_BLK, 512, 0, stream>>>(x, dom, scale_shift, out);
}